// Round 1
// baseline (625.731 us; speedup 1.0000x reference)
//
#include <hip/hip_runtime.h>

// Shapes: B=8, Q=1, T=2048, H=512, V=32000
#define Hdim 512
#define Bdim 8
#define Tdim 2048
#define Vdim 32000
#define OUTW (Vdim + Tdim)   // 34048
#define DEC_BLOCKS (Vdim / 128)   // 250
#define REP_BLOCKS ((Bdim * Tdim) / 128)  // 128

// qp[b,k] = sum_h x[b,h] * w1[k,h] + b1[k]   (b1 folded in here)
__global__ __launch_bounds__(64) void qproj_kernel(
    const float* __restrict__ x, const float* __restrict__ w1,
    const float* __restrict__ b1, float* __restrict__ qp)
{
    const int b = blockIdx.x >> 9;
    const int k = blockIdx.x & 511;
    const int lane = threadIdx.x;
    const float* xr = x + b * Hdim;
    const float* wr = w1 + (size_t)k * (2 * Hdim);   // w1q = w1[:, :H]
    float s = 0.f;
#pragma unroll
    for (int it = 0; it < Hdim / 64; ++it)
        s += xr[lane + it * 64] * wr[lane + it * 64];
#pragma unroll
    for (int off = 32; off > 0; off >>= 1)
        s += __shfl_down(s, off);
    if (lane == 0) qp[b * Hdim + k] = s + b1[k];
}

// One block computes 128 rows of A x w1t^T (K=512 output cols, in 8 chunks of
// 64), fusing the relu(P + qp[b]) . w2 reduction so neither d_proj nor t_proj
// is materialized.
// Blocks [0, 250): decoder part (A = decoder_weight, all 8 batches).
// Blocks [250, 378): repair part (A = target_embeds flat, single batch + mask).
__global__ __launch_bounds__(256, 2) void fused_kernel(
    const float* __restrict__ dec, const float* __restrict__ tgt,
    const float* __restrict__ w1, const float* __restrict__ qp,
    const float* __restrict__ w2, const float* __restrict__ mask,
    float* __restrict__ out)
{
    // staging buffers (transposed for b128 reads) unioned with the P tile:
    // they are live in disjoint phases separated by barriers.
    __shared__ __align__(16) union SU {
        struct { float As[16][136]; float Ws[16][72]; } ld;  // [h][row]
        float Pt[128][68];                                   // [m][k_local]
    } s;
    __shared__ float qps[Bdim][Hdim];
    __shared__ float w2s[Hdim];

    const int tid = threadIdx.x;
    const bool is_dec = (blockIdx.x < DEC_BLOCKS);
    const int m0 = (is_dec ? blockIdx.x : (blockIdx.x - DEC_BLOCKS)) * 128;
    const float* __restrict__ A = is_dec ? dec : tgt;
    const int bb = is_dec ? 0 : (m0 >> 11);   // repair batch (T=2048 rows/batch)
    const int t0 = m0 & 2047;

    for (int i = tid; i < Bdim * Hdim; i += 256) qps[i >> 9][i & 511] = qp[i];
    for (int i = tid; i < Hdim; i += 256) w2s[i] = w2[i];

    const int tx = tid & 15;   // covers 64 k-cols, 4 each
    const int ty = tid >> 4;   // covers 128 m-rows, 8 each
    const int er = tid >> 1;          // epilogue row 0..127
    const int eh = (tid & 1) * 32;    // epilogue k-half

    float accb[8];
#pragma unroll
    for (int b = 0; b < 8; ++b) accb[b] = 0.f;

    for (int k0 = 0; k0 < Hdim; k0 += 64) {
        float acc[8][4];
#pragma unroll
        for (int i = 0; i < 8; ++i)
#pragma unroll
            for (int j = 0; j < 4; ++j) acc[i][j] = 0.f;

        for (int h0 = 0; h0 < Hdim; h0 += 16) {
            __syncthreads();   // prev compute / prev epilogue done with union
            // A tile: 128 rows x 16 h  (2 float4 per thread, stored transposed)
#pragma unroll
            for (int it = 0; it < 2; ++it) {
                const int idx = tid + it * 256;
                const int r = idx >> 2, c4 = idx & 3;
                const float4 v = *(const float4*)(A + (size_t)(m0 + r) * Hdim + h0 + c4 * 4);
                s.ld.As[c4 * 4 + 0][r] = v.x;
                s.ld.As[c4 * 4 + 1][r] = v.y;
                s.ld.As[c4 * 4 + 2][r] = v.z;
                s.ld.As[c4 * 4 + 3][r] = v.w;
            }
            // W tile: 64 k-rows x 16 h of w1t  (w1t[k,h] = w1[k*1024 + 512 + h])
            {
                const int r = tid >> 2, c4 = tid & 3;
                const float4 v = *(const float4*)(w1 + (size_t)(k0 + r) * 1024 + 512 + h0 + c4 * 4);
                s.ld.Ws[c4 * 4 + 0][r] = v.x;
                s.ld.Ws[c4 * 4 + 1][r] = v.y;
                s.ld.Ws[c4 * 4 + 2][r] = v.z;
                s.ld.Ws[c4 * 4 + 3][r] = v.w;
            }
            __syncthreads();
#pragma unroll
            for (int hh = 0; hh < 16; ++hh) {
                const float4 a0 = *(const float4*)&s.ld.As[hh][ty * 8];
                const float4 a1 = *(const float4*)&s.ld.As[hh][ty * 8 + 4];
                const float4 b0 = *(const float4*)&s.ld.Ws[hh][tx * 4];
                const float av[8] = {a0.x, a0.y, a0.z, a0.w, a1.x, a1.y, a1.z, a1.w};
                const float bv[4] = {b0.x, b0.y, b0.z, b0.w};
#pragma unroll
                for (int i = 0; i < 8; ++i)
#pragma unroll
                    for (int j = 0; j < 4; ++j)
                        acc[i][j] = fmaf(av[i], bv[j], acc[i][j]);
            }
        }
        __syncthreads();   // done reading As/Ws; union becomes Pt
#pragma unroll
        for (int i = 0; i < 8; ++i) {
            float4 v = make_float4(acc[i][0], acc[i][1], acc[i][2], acc[i][3]);
            *(float4*)&s.Pt[ty * 8 + i][tx * 4] = v;
        }
        __syncthreads();

        // epilogue: acc[b, row] += sum_k relu(P + qp[b, k]) * w2[k]
        float p[32];
#pragma unroll
        for (int k4 = 0; k4 < 8; ++k4) {
            const float4 v = *(const float4*)&s.Pt[er][eh + k4 * 4];
            p[k4 * 4 + 0] = v.x; p[k4 * 4 + 1] = v.y;
            p[k4 * 4 + 2] = v.z; p[k4 * 4 + 3] = v.w;
        }
        const int nb = is_dec ? 8 : 1;
        for (int b = 0; b < nb; ++b) {
            const int qb = is_dec ? b : bb;
            float sa = 0.f;
#pragma unroll
            for (int kk = 0; kk < 32; ++kk)
                sa = fmaf(fmaxf(p[kk] + qps[qb][k0 + eh + kk], 0.f),
                          w2s[k0 + eh + kk], sa);
            accb[b] += sa;
        }
    }

    // combine the two k-halves (adjacent lanes) and store
#pragma unroll
    for (int b = 0; b < 8; ++b) accb[b] += __shfl_down(accb[b], 1);
    if ((tid & 1) == 0) {
        const int r = er;
        if (is_dec) {
#pragma unroll
            for (int b = 0; b < 8; ++b)
                out[(size_t)b * OUTW + m0 + r] = accb[b];
        } else {
            const float mv = mask[bb * Tdim + t0 + r];
            out[(size_t)bb * OUTW + Vdim + t0 + r] =
                mv * accb[0] - 1000.f * (1.f - mv);
        }
    }
}

extern "C" void kernel_launch(void* const* d_in, const int* in_sizes, int n_in,
                              void* d_out, int out_size, void* d_ws, size_t ws_size,
                              hipStream_t stream) {
    const float* input_embeds  = (const float*)d_in[0];  // (8,1,512)
    const float* target_embeds = (const float*)d_in[1];  // (8,2048,512)
    const float* input_mask    = (const float*)d_in[2];  // (8,2048)
    const float* w1            = (const float*)d_in[3];  // (512,1024)
    const float* b1            = (const float*)d_in[4];  // (512,)
    const float* w2            = (const float*)d_in[5];  // (512,)
    const float* decoder_w     = (const float*)d_in[6];  // (32000,512)
    float* out = (float*)d_out;                          // (8, 34048)
    float* qp  = (float*)d_ws;                           // 8*512 floats

    qproj_kernel<<<Bdim * Hdim, 64, 0, stream>>>(input_embeds, w1, b1, qp);
    fused_kernel<<<DEC_BLOCKS + REP_BLOCKS, 256, 0, stream>>>(
        decoder_w, target_embeds, w1, qp, w2, input_mask, out);
}

// Round 2
// 289.956 us; speedup vs baseline: 2.1580x; 2.1580x over previous
//
#include <hip/hip_runtime.h>

// Shapes: B=8, Q=1, T=2048, H=512, V=32000
#define Hdim 512
#define Bdim 8
#define Tdim 2048
#define Vdim 32000
#define OUTW (Vdim + Tdim)        // 34048
#define DEC_TILES (Vdim / 128)    // 250
#define REP_TILES ((Bdim * Tdim) / 128)  // 128
#define NTILES (DEC_TILES + REP_TILES)   // 378

typedef __attribute__((ext_vector_type(8))) short short8;
typedef __attribute__((ext_vector_type(16))) float f32x16;

// ---------------- fp32 -> bf16 (RNE) conversion pass ----------------
__device__ __forceinline__ unsigned bfr(float f) {
    union { float f; unsigned u; } x; x.f = f;
    return (x.u + 0x7FFFu + ((x.u >> 16) & 1u)) >> 16;
}

__global__ __launch_bounds__(256) void cvt_kernel(const float* __restrict__ src,
                                                  unsigned short* __restrict__ dst,
                                                  int n8) {
    int i = blockIdx.x * 256 + threadIdx.x;
    if (i >= n8) return;
    const float4* s = (const float4*)src + (size_t)i * 2;
    float4 v0 = s[0], v1 = s[1];
    uint4 o;
    o.x = bfr(v0.x) | (bfr(v0.y) << 16);
    o.y = bfr(v0.z) | (bfr(v0.w) << 16);
    o.z = bfr(v1.x) | (bfr(v1.y) << 16);
    o.w = bfr(v1.z) | (bfr(v1.w) << 16);
    ((uint4*)dst)[i] = o;
}

// ---------------- qp[b,k] = x[b,:] . w1q[k,:] + b1[k] (fp32) ----------------
__global__ __launch_bounds__(64) void qproj_kernel(
    const float* __restrict__ x, const float* __restrict__ w1,
    const float* __restrict__ b1, float* __restrict__ qp)
{
    const int b = blockIdx.x >> 9;
    const int k = blockIdx.x & 511;
    const int lane = threadIdx.x;
    const float* xr = x + b * Hdim;
    const float* wr = w1 + (size_t)k * (2 * Hdim);
    float s = 0.f;
#pragma unroll
    for (int it = 0; it < Hdim / 64; ++it)
        s += xr[lane + it * 64] * wr[lane + it * 64];
#pragma unroll
    for (int off = 32; off > 0; off >>= 1) s += __shfl_down(s, off);
    if (lane == 0) qp[b * Hdim + k] = s + b1[k];
}

// ---------------- init out: decoder=0, repair=-1000*(1-mask) ----------------
__global__ __launch_bounds__(256) void init_out(const float* __restrict__ mask,
                                                float* __restrict__ out) {
    int i = blockIdx.x * 256 + threadIdx.x;
    if (i >= Bdim * OUTW) return;
    int b = i / OUTW, c = i % OUTW;
    out[i] = (c < Vdim) ? 0.f : -1000.f * (1.f - mask[b * Tdim + (c - Vdim)]);
}

// ---------------- fused MFMA GEMM + relu-dot epilogue ----------------
// grid = NTILES * 4. Block computes 128 rows x 128 cols of P = A . w1t^T,
// then accumulates sum_n relu(P + qp[b][n]) * w2[n] into out via atomicAdd.
__global__ __launch_bounds__(256, 2) void gemm_fused(
    const unsigned short* __restrict__ Adec,   // 32000 x 512 bf16
    const unsigned short* __restrict__ Atgt,   // 16384 x 512 bf16
    const unsigned short* __restrict__ Wbf,    // 512 x 1024 bf16 (full w1)
    const float* __restrict__ qp,              // 8 x 512
    const float* __restrict__ w2,              // 512
    const float* __restrict__ mask,            // 8 x 2048
    float* __restrict__ out)                   // 8 x 34048
{
    // staging (XOR-swizzled k-groups) unioned with a half P-tile
    __shared__ union {
        struct { unsigned short A[128][64]; unsigned short W[128][64]; } st;
        float Pt[64][128];   // swizzled cols: chunk4' = chunk4 ^ (row&7)
    } u;
    __shared__ float qps[Bdim][128];
    __shared__ float w2s[128];

    const int tid  = threadIdx.x;
    const int lane = tid & 63;
    const int w    = tid >> 6;

    const int mt = blockIdx.x >> 2;
    const int n0 = (blockIdx.x & 3) << 7;
    const bool is_dec = (mt < DEC_TILES);
    const int m0 = (is_dec ? mt : mt - DEC_TILES) << 7;
    const unsigned short* __restrict__ A = is_dec ? Adec : Atgt;
    const int bb = is_dec ? 0 : (m0 >> 11);
    const int t0 = m0 & 2047;

    for (int i = tid; i < Bdim * 128; i += 256)
        qps[i >> 7][i & 127] = qp[(i >> 7) * Hdim + n0 + (i & 127)];
    if (tid < 128) w2s[tid] = w2[n0 + tid];

    // staging addresses: lane L loads 16B; lands at LDS base + L*16.
    // physical col8 = L&7 holds logical k-group (L&7)^(L>>3)  (row&7 = L>>3)
    const int sr = lane >> 3;
    const int sc = (lane & 7) ^ sr;
    const unsigned short* gA = A   + (size_t)(m0 + w * 32 + sr) * 512  + sc * 8;
    const unsigned short* gW = Wbf + (size_t)(n0 + w * 32 + sr) * 1024 + 512 + sc * 8;

    f32x16 acc00, acc01, acc10, acc11;
#pragma unroll
    for (int i = 0; i < 16; ++i) { acc00[i] = 0.f; acc01[i] = 0.f; acc10[i] = 0.f; acc11[i] = 0.f; }

    const int wm  = (w & 1) << 6;   // wave 64x64 subtile origin
    const int wn  = (w >> 1) << 6;
    const int l31 = lane & 31;
    const int kh  = lane >> 5;      // k-half within MFMA frag

    for (int h0 = 0; h0 < Hdim; h0 += 64) {
        __syncthreads();
#pragma unroll
        for (int i = 0; i < 4; ++i) {
            __builtin_amdgcn_global_load_lds(
                (const __attribute__((address_space(1))) unsigned int*)(gA + i * 8 * 512),
                (__attribute__((address_space(3))) unsigned int*)(&u.st.A[w * 32 + i * 8][0]),
                16, 0, 0);
            __builtin_amdgcn_global_load_lds(
                (const __attribute__((address_space(1))) unsigned int*)(gW + i * 8 * 1024),
                (__attribute__((address_space(3))) unsigned int*)(&u.st.W[w * 32 + i * 8][0]),
                16, 0, 0);
        }
        gA += 64; gW += 64;
        __syncthreads();
#pragma unroll
        for (int s = 0; s < 4; ++s) {
            const int g  = s * 2 + kh;                 // k-group 0..7
            const int ca = ((g ^ (l31 & 7)) << 3);     // swizzled col offset (elems)
            short8 a0 = *(const short8*)&u.st.A[wm + l31][ca];
            short8 a1 = *(const short8*)&u.st.A[wm + l31 + 32][ca];
            short8 b0 = *(const short8*)&u.st.W[wn + l31][ca];
            short8 b1 = *(const short8*)&u.st.W[wn + l31 + 32][ca];
            acc00 = __builtin_amdgcn_mfma_f32_32x32x16_bf16(a0, b0, acc00, 0, 0, 0);
            acc01 = __builtin_amdgcn_mfma_f32_32x32x16_bf16(a0, b1, acc01, 0, 0, 0);
            acc10 = __builtin_amdgcn_mfma_f32_32x32x16_bf16(a1, b0, acc10, 0, 0, 0);
            acc11 = __builtin_amdgcn_mfma_f32_32x32x16_bf16(a1, b1, acc11, 0, 0, 0);
        }
    }

    // ---- epilogue: two row-halves through the unioned P-tile ----
    const int rg = tid >> 3;   // row group: rows rg*2, rg*2+1 (within half)
    const int sl = tid & 7;    // col slice
    const int nb = is_dec ? 8 : 1;

    for (int half = 0; half < 2; ++half) {
        __syncthreads();   // prior phase done with union
        if ((w & 1) == half) {
            // C/D layout (verified m74/m101): col=lane&31, row=(r&3)+8*(r>>2)+4*(lane>>5)
#pragma unroll
            for (int r = 0; r < 16; ++r) {
                const int ra  = (r & 3) + ((r >> 2) << 3) + (kh << 2);  // 0..31
                const int rb2 = ra + 32;
                const int c0 = wn + l31, c1 = wn + 32 + l31;
                u.Pt[ra ][((((c0 >> 2) ^ (ra  & 7)) << 2) | (c0 & 3))] = acc00[r];
                u.Pt[ra ][((((c1 >> 2) ^ (ra  & 7)) << 2) | (c1 & 3))] = acc01[r];
                u.Pt[rb2][((((c0 >> 2) ^ (rb2 & 7)) << 2) | (c0 & 3))] = acc10[r];
                u.Pt[rb2][((((c1 >> 2) ^ (rb2 & 7)) << 2) | (c1 & 3))] = acc11[r];
            }
        }
        __syncthreads();

        float accb[8][2];
#pragma unroll
        for (int b = 0; b < 8; ++b) { accb[b][0] = 0.f; accb[b][1] = 0.f; }

#pragma unroll
        for (int c4 = 0; c4 < 4; ++c4) {
            const int c = (sl << 2) + (c4 << 5);   // logical col
            const float4 wv = *(const float4*)&w2s[c];
            float4 qv[8];
            for (int b = 0; b < nb; ++b)
                qv[b] = *(const float4*)&qps[is_dec ? b : bb][c];
#pragma unroll
            for (int rl = 0; rl < 2; ++rl) {
                const int row = (rg << 1) + rl;
                const int pc  = ((sl ^ (row & 7)) + (c4 << 3)) << 2;
                const float4 pv = *(const float4*)&u.Pt[row][pc];
                for (int b = 0; b < nb; ++b) {
                    float t;
                    t  = fmaxf(pv.x + qv[b].x, 0.f) * wv.x;
                    t += fmaxf(pv.y + qv[b].y, 0.f) * wv.y;
                    t += fmaxf(pv.z + qv[b].z, 0.f) * wv.z;
                    t += fmaxf(pv.w + qv[b].w, 0.f) * wv.w;
                    accb[b][rl] += t;
                }
            }
        }

        // reduce the 8 col-slices (lanes sl=0..7 are consecutive)
        for (int off = 1; off < 8; off <<= 1)
            for (int b = 0; b < nb; ++b) {
                accb[b][0] += __shfl_xor(accb[b][0], off);
                accb[b][1] += __shfl_xor(accb[b][1], off);
            }

        if (sl == 0) {
#pragma unroll
            for (int rl = 0; rl < 2; ++rl) {
                const int rowin = (half << 6) + (rg << 1) + rl;
                if (is_dec) {
                    for (int b = 0; b < 8; ++b)
                        atomicAdd(&out[(size_t)b * OUTW + m0 + rowin], accb[b][rl]);
                } else {
                    const float mv = mask[bb * Tdim + t0 + rowin];
                    atomicAdd(&out[(size_t)bb * OUTW + Vdim + t0 + rowin],
                              mv * accb[0][rl]);
                }
            }
        }
    }
}

extern "C" void kernel_launch(void* const* d_in, const int* in_sizes, int n_in,
                              void* d_out, int out_size, void* d_ws, size_t ws_size,
                              hipStream_t stream) {
    const float* input_embeds  = (const float*)d_in[0];  // (8,1,512)
    const float* target_embeds = (const float*)d_in[1];  // (8,2048,512)
    const float* input_mask    = (const float*)d_in[2];  // (8,2048)
    const float* w1            = (const float*)d_in[3];  // (512,1024)
    const float* b1            = (const float*)d_in[4];  // (512,)
    const float* w2            = (const float*)d_in[5];  // (512,)
    const float* decoder_w     = (const float*)d_in[6];  // (32000,512)
    float* out = (float*)d_out;

    // ws layout: qp (16 KB) | dec bf16 (32.77 MB) | tgt bf16 (16.78 MB) | w1 bf16 (1 MB)
    float* qp = (float*)d_ws;
    unsigned short* decbf = (unsigned short*)((char*)d_ws + 16384);
    unsigned short* tgtbf = decbf + (size_t)Vdim * Hdim;
    unsigned short* w1bf  = tgtbf + (size_t)Bdim * Tdim * Hdim;

    cvt_kernel<<<(Vdim * Hdim / 8 + 255) / 256, 256, 0, stream>>>(decoder_w, decbf, Vdim * Hdim / 8);
    cvt_kernel<<<(Bdim * Tdim * Hdim / 8 + 255) / 256, 256, 0, stream>>>(target_embeds, tgtbf, Bdim * Tdim * Hdim / 8);
    cvt_kernel<<<(Hdim * 1024 / 8 + 255) / 256, 256, 0, stream>>>(w1, w1bf, Hdim * 1024 / 8);
    qproj_kernel<<<Bdim * Hdim, 64, 0, stream>>>(input_embeds, w1, b1, qp);
    init_out<<<(Bdim * OUTW + 255) / 256, 256, 0, stream>>>(input_mask, out);
    gemm_fused<<<NTILES * 4, 256, 0, stream>>>(decbf, tgtbf, w1bf, qp, w2, input_mask, out);
}

// Round 3
// 284.305 us; speedup vs baseline: 2.2009x; 1.0199x over previous
//
#include <hip/hip_runtime.h>

// Shapes: B=8, Q=1, T=2048, H=512, V=32000
#define Hdim 512
#define Bdim 8
#define Tdim 2048
#define Vdim 32000
#define OUTW (Vdim + Tdim)        // 34048
#define DEC_TILES (Vdim / 128)    // 250
#define REP_TILES ((Bdim * Tdim) / 128)  // 128
#define NTILES (DEC_TILES + REP_TILES)   // 378

typedef __attribute__((ext_vector_type(8))) short short8;
typedef __attribute__((ext_vector_type(16))) float f32x16;

// ---------------- fp32 -> bf16 (RNE) conversion, all 3 tensors ----------------
__device__ __forceinline__ unsigned bfr(float f) {
    union { float f; unsigned u; } x; x.f = f;
    return (x.u + 0x7FFFu + ((x.u >> 16) & 1u)) >> 16;
}

#define N8_DEC (Vdim * Hdim / 8)              // 2,048,000
#define N8_TGT (Bdim * Tdim * Hdim / 8)       // 1,048,576
#define N8_W1  (Hdim * 1024 / 8)              // 65,536
#define N8_ALL (N8_DEC + N8_TGT + N8_W1)      // 3,162,112

__global__ __launch_bounds__(256) void cvt_all(
    const float* __restrict__ dec, const float* __restrict__ tgt,
    const float* __restrict__ w1,
    unsigned short* __restrict__ decbf, unsigned short* __restrict__ tgtbf,
    unsigned short* __restrict__ w1bf)
{
    int i = blockIdx.x * 256 + threadIdx.x;
    if (i >= N8_ALL) return;
    const float* src; unsigned short* dst; int j;
    if (i < N8_DEC)                { src = dec; dst = decbf; j = i; }
    else if (i < N8_DEC + N8_TGT)  { src = tgt; dst = tgtbf; j = i - N8_DEC; }
    else                           { src = w1;  dst = w1bf;  j = i - N8_DEC - N8_TGT; }
    const float4* s = (const float4*)src + (size_t)j * 2;
    float4 v0 = s[0], v1 = s[1];
    uint4 o;
    o.x = bfr(v0.x) | (bfr(v0.y) << 16);
    o.y = bfr(v0.z) | (bfr(v0.w) << 16);
    o.z = bfr(v1.x) | (bfr(v1.y) << 16);
    o.w = bfr(v1.z) | (bfr(v1.w) << 16);
    ((uint4*)dst)[j] = o;
}

// ---------------- qp[b,k] = x[b,:] . w1q[k,:] + b1[k] (fp32) ----------------
__global__ __launch_bounds__(64) void qproj_kernel(
    const float* __restrict__ x, const float* __restrict__ w1,
    const float* __restrict__ b1, float* __restrict__ qp)
{
    const int b = blockIdx.x >> 9;
    const int k = blockIdx.x & 511;
    const int lane = threadIdx.x;
    const float* xr = x + b * Hdim;
    const float* wr = w1 + (size_t)k * (2 * Hdim);
    float s = 0.f;
#pragma unroll
    for (int it = 0; it < Hdim / 64; ++it)
        s += xr[lane + it * 64] * wr[lane + it * 64];
#pragma unroll
    for (int off = 32; off > 0; off >>= 1) s += __shfl_down(s, off);
    if (lane == 0) qp[b * Hdim + k] = s + b1[k];
}

// ---------------- fused MFMA GEMM + relu-dot epilogue ----------------
// grid = NTILES * 4. Block computes 128 rows x 128 cols of P = A . w1t^T,
// then reduces sum_n relu(P + qp[b][n]) * w2[n] into its private partial
// slice part[chunk][b][col] (no atomics).
__global__ __launch_bounds__(256, 2) void gemm_fused(
    const unsigned short* __restrict__ Adec,   // 32000 x 512 bf16
    const unsigned short* __restrict__ Atgt,   // 16384 x 512 bf16
    const unsigned short* __restrict__ Wbf,    // 512 x 1024 bf16 (full w1)
    const float* __restrict__ qp,              // 8 x 512
    const float* __restrict__ w2,              // 512
    float* __restrict__ part)                  // 4 x 8 x 34048
{
    // staging (XOR-swizzled k-groups) unioned with a half P-tile
    __shared__ union {
        struct { unsigned short A[128][64]; unsigned short W[128][64]; } st;
        float Pt[64][128];   // swizzled cols: chunk4' = chunk4 ^ (row&7)
    } u;
    __shared__ float qps[Bdim][128];
    __shared__ float w2s[128];

    const int tid  = threadIdx.x;
    const int lane = tid & 63;
    const int w    = tid >> 6;

    const int mt    = blockIdx.x >> 2;
    const int chunk = blockIdx.x & 3;
    const int n0    = chunk << 7;
    const bool is_dec = (mt < DEC_TILES);
    const int m0 = (is_dec ? mt : mt - DEC_TILES) << 7;
    const unsigned short* __restrict__ A = is_dec ? Adec : Atgt;
    const int bb = is_dec ? 0 : (m0 >> 11);
    const int t0 = m0 & 2047;

    for (int i = tid; i < Bdim * 128; i += 256)
        qps[i >> 7][i & 127] = qp[(i >> 7) * Hdim + n0 + (i & 127)];
    if (tid < 128) w2s[tid] = w2[n0 + tid];

    // staging addresses: lane L loads 16B; lands at LDS base + L*16.
    // physical col8 = L&7 holds logical k-group (L&7)^(L>>3)  (row&7 = L>>3)
    const int sr = lane >> 3;
    const int sc = (lane & 7) ^ sr;
    const unsigned short* gA = A   + (size_t)(m0 + w * 32 + sr) * 512  + sc * 8;
    const unsigned short* gW = Wbf + (size_t)(n0 + w * 32 + sr) * 1024 + 512 + sc * 8;

    f32x16 acc00, acc01, acc10, acc11;
#pragma unroll
    for (int i = 0; i < 16; ++i) { acc00[i] = 0.f; acc01[i] = 0.f; acc10[i] = 0.f; acc11[i] = 0.f; }

    const int wm  = (w & 1) << 6;   // wave 64x64 subtile origin
    const int wn  = (w >> 1) << 6;
    const int l31 = lane & 31;
    const int kh  = lane >> 5;      // k-half within MFMA frag

    for (int h0 = 0; h0 < Hdim; h0 += 64) {
        __syncthreads();
#pragma unroll
        for (int i = 0; i < 4; ++i) {
            __builtin_amdgcn_global_load_lds(
                (const __attribute__((address_space(1))) unsigned int*)(gA + i * 8 * 512),
                (__attribute__((address_space(3))) unsigned int*)(&u.st.A[w * 32 + i * 8][0]),
                16, 0, 0);
            __builtin_amdgcn_global_load_lds(
                (const __attribute__((address_space(1))) unsigned int*)(gW + i * 8 * 1024),
                (__attribute__((address_space(3))) unsigned int*)(&u.st.W[w * 32 + i * 8][0]),
                16, 0, 0);
        }
        gA += 64; gW += 64;
        __syncthreads();
#pragma unroll
        for (int s = 0; s < 4; ++s) {
            const int g  = s * 2 + kh;                 // k-group 0..7
            const int ca = ((g ^ (l31 & 7)) << 3);     // swizzled col offset (elems)
            short8 a0 = *(const short8*)&u.st.A[wm + l31][ca];
            short8 a1 = *(const short8*)&u.st.A[wm + l31 + 32][ca];
            short8 b0 = *(const short8*)&u.st.W[wn + l31][ca];
            short8 b1 = *(const short8*)&u.st.W[wn + l31 + 32][ca];
            acc00 = __builtin_amdgcn_mfma_f32_32x32x16_bf16(a0, b0, acc00, 0, 0, 0);
            acc01 = __builtin_amdgcn_mfma_f32_32x32x16_bf16(a0, b1, acc01, 0, 0, 0);
            acc10 = __builtin_amdgcn_mfma_f32_32x32x16_bf16(a1, b0, acc10, 0, 0, 0);
            acc11 = __builtin_amdgcn_mfma_f32_32x32x16_bf16(a1, b1, acc11, 0, 0, 0);
        }
    }

    // ---- epilogue: two row-halves through the unioned P-tile ----
    const int rg = tid >> 3;   // row group: rows rg*2, rg*2+1 (within half)
    const int sl = tid & 7;    // col slice
    const int nb = is_dec ? 8 : 1;

    for (int half = 0; half < 2; ++half) {
        __syncthreads();   // prior phase done with union
        if ((w & 1) == half) {
            // C/D layout (verified m74/m101): col=lane&31, row=(r&3)+8*(r>>2)+4*(lane>>5)
#pragma unroll
            for (int r = 0; r < 16; ++r) {
                const int ra  = (r & 3) + ((r >> 2) << 3) + (kh << 2);  // 0..31
                const int rb2 = ra + 32;
                const int c0 = wn + l31, c1 = wn + 32 + l31;
                u.Pt[ra ][((((c0 >> 2) ^ (ra  & 7)) << 2) | (c0 & 3))] = acc00[r];
                u.Pt[ra ][((((c1 >> 2) ^ (ra  & 7)) << 2) | (c1 & 3))] = acc01[r];
                u.Pt[rb2][((((c0 >> 2) ^ (rb2 & 7)) << 2) | (c0 & 3))] = acc10[r];
                u.Pt[rb2][((((c1 >> 2) ^ (rb2 & 7)) << 2) | (c1 & 3))] = acc11[r];
            }
        }
        __syncthreads();

        float accb[8][2];
#pragma unroll
        for (int b = 0; b < 8; ++b) { accb[b][0] = 0.f; accb[b][1] = 0.f; }

#pragma unroll
        for (int c4 = 0; c4 < 4; ++c4) {
            const int c = (sl << 2) + (c4 << 5);   // logical col
            const float4 wv = *(const float4*)&w2s[c];
            float4 qv[8];
            for (int b = 0; b < nb; ++b)
                qv[b] = *(const float4*)&qps[is_dec ? b : bb][c];
#pragma unroll
            for (int rl = 0; rl < 2; ++rl) {
                const int row = (rg << 1) + rl;
                const int pc  = ((sl ^ (row & 7)) + (c4 << 3)) << 2;
                const float4 pv = *(const float4*)&u.Pt[row][pc];
                for (int b = 0; b < nb; ++b) {
                    float t;
                    t  = fmaxf(pv.x + qv[b].x, 0.f) * wv.x;
                    t += fmaxf(pv.y + qv[b].y, 0.f) * wv.y;
                    t += fmaxf(pv.z + qv[b].z, 0.f) * wv.z;
                    t += fmaxf(pv.w + qv[b].w, 0.f) * wv.w;
                    accb[b][rl] += t;
                }
            }
        }

        // reduce the 8 col-slices (lanes sl=0..7 are consecutive)
        for (int off = 1; off < 8; off <<= 1)
            for (int b = 0; b < nb; ++b) {
                accb[b][0] += __shfl_xor(accb[b][0], off);
                accb[b][1] += __shfl_xor(accb[b][1], off);
            }

        if (sl == 0) {
#pragma unroll
            for (int rl = 0; rl < 2; ++rl) {
                const int rowin = (half << 6) + (rg << 1) + rl;
                if (is_dec) {
                    for (int b = 0; b < 8; ++b)
                        part[((size_t)(chunk * 8 + b)) * OUTW + m0 + rowin] = accb[b][rl];
                } else {
                    part[((size_t)(chunk * 8 + bb)) * OUTW + Vdim + t0 + rowin] = accb[0][rl];
                }
            }
        }
    }
}

// ---------------- sum the 4 chunk-partials, apply mask, write out ----------------
__global__ __launch_bounds__(256) void reduce_out(
    const float* __restrict__ part, const float* __restrict__ mask,
    float* __restrict__ out)
{
    int i = blockIdx.x * 256 + threadIdx.x;
    if (i >= Bdim * OUTW) return;
    int b = i / OUTW, c = i % OUTW;
    float s = 0.f;
#pragma unroll
    for (int ch = 0; ch < 4; ++ch)
        s += part[((size_t)(ch * 8 + b)) * OUTW + c];
    if (c >= Vdim) {
        const float mv = mask[b * Tdim + (c - Vdim)];
        s = mv * s - 1000.f * (1.f - mv);
    }
    out[i] = s;
}

extern "C" void kernel_launch(void* const* d_in, const int* in_sizes, int n_in,
                              void* d_out, int out_size, void* d_ws, size_t ws_size,
                              hipStream_t stream) {
    const float* input_embeds  = (const float*)d_in[0];  // (8,1,512)
    const float* target_embeds = (const float*)d_in[1];  // (8,2048,512)
    const float* input_mask    = (const float*)d_in[2];  // (8,2048)
    const float* w1            = (const float*)d_in[3];  // (512,1024)
    const float* b1            = (const float*)d_in[4];  // (512,)
    const float* w2            = (const float*)d_in[5];  // (512,)
    const float* decoder_w     = (const float*)d_in[6];  // (32000,512)
    float* out = (float*)d_out;

    // ws layout: qp 16 KB | partials 4x8x34048 f32 (4.36 MB) | dec bf16 | tgt bf16 | w1 bf16
    float* qp   = (float*)d_ws;
    float* part = (float*)((char*)d_ws + 16384);
    unsigned short* decbf = (unsigned short*)((char*)d_ws + 16384 + (size_t)4 * Bdim * OUTW * 4);
    unsigned short* tgtbf = decbf + (size_t)Vdim * Hdim;
    unsigned short* w1bf  = tgtbf + (size_t)Bdim * Tdim * Hdim;

    cvt_all<<<(N8_ALL + 255) / 256, 256, 0, stream>>>(
        decoder_w, target_embeds, w1, decbf, tgtbf, w1bf);
    qproj_kernel<<<Bdim * Hdim, 64, 0, stream>>>(input_embeds, w1, b1, qp);
    gemm_fused<<<NTILES * 4, 256, 0, stream>>>(decbf, tgtbf, w1bf, qp, w2, part);
    reduce_out<<<(Bdim * OUTW + 255) / 256, 256, 0, stream>>>(part, input_mask, out);
}

// Round 4
// 215.193 us; speedup vs baseline: 2.9078x; 1.3212x over previous
//
#include <hip/hip_runtime.h>

// Shapes: B=8, Q=1, T=2048, H=512, V=32000
#define Hdim 512
#define Bdim 8
#define Tdim 2048
#define Vdim 32000
#define OUTW (Vdim + Tdim)        // 34048
#define DEC_TILES (Vdim / 128)    // 250
#define REP_TILES ((Bdim * Tdim) / 128)  // 128
#define NTILES (DEC_TILES + REP_TILES)   // 378
#define PROWS (Vdim + Bdim * Tdim)       // 48384

typedef __attribute__((ext_vector_type(8))) short short8;
typedef __attribute__((ext_vector_type(16))) float f32x16;

__device__ __forceinline__ unsigned bfr(float f) {
    union { float f; unsigned u; } x; x.f = f;
    return (x.u + 0x7FFFu + ((x.u >> 16) & 1u)) >> 16;
}
__device__ __forceinline__ float lo16f(unsigned u) { return __uint_as_float(u << 16); }
__device__ __forceinline__ float hi16f(unsigned u) { return __uint_as_float(u & 0xffff0000u); }

#define N8_DEC (Vdim * Hdim / 8)              // 2,048,000
#define N8_TGT (Bdim * Tdim * Hdim / 8)       // 1,048,576
#define N8_W1  (Hdim * 1024 / 8)              // 65,536
#define N8_ALL (N8_DEC + N8_TGT + N8_W1)      // 3,162,112
#define CVT_BLOCKS (N8_ALL / 256)             // 12352 (exact)
#define QP_BLOCKS (Bdim * Hdim / 4)           // 1024 blocks, 4 waves each

// ---------------- prep: bf16 conversion + qp in one launch ----------------
__global__ __launch_bounds__(256) void prep_kernel(
    const float* __restrict__ dec, const float* __restrict__ tgt,
    const float* __restrict__ w1, const float* __restrict__ x,
    const float* __restrict__ b1,
    unsigned short* __restrict__ decbf, unsigned short* __restrict__ tgtbf,
    unsigned short* __restrict__ w1bf, float* __restrict__ qp)
{
    const int bid = blockIdx.x;
    if (bid < CVT_BLOCKS) {
        int i = bid * 256 + threadIdx.x;
        const float* src; unsigned short* dst; int j;
        if (i < N8_DEC)                { src = dec; dst = decbf; j = i; }
        else if (i < N8_DEC + N8_TGT)  { src = tgt; dst = tgtbf; j = i - N8_DEC; }
        else                           { src = w1;  dst = w1bf;  j = i - N8_DEC - N8_TGT; }
        const float4* s = (const float4*)src + (size_t)j * 2;
        float4 v0 = s[0], v1 = s[1];
        uint4 o;
        o.x = bfr(v0.x) | (bfr(v0.y) << 16);
        o.y = bfr(v0.z) | (bfr(v0.w) << 16);
        o.z = bfr(v1.x) | (bfr(v1.y) << 16);
        o.w = bfr(v1.z) | (bfr(v1.w) << 16);
        ((uint4*)dst)[j] = o;
    } else {
        // qp[b,k] = x[b,:].w1q[k,:] + b1[k], one wave per (b,k)
        const int widx = (bid - CVT_BLOCKS) * 4 + (threadIdx.x >> 6);
        const int lane = threadIdx.x & 63;
        const int b = widx >> 9, k = widx & 511;
        const float4* xr = (const float4*)(x + b * Hdim);
        const float4* wr = (const float4*)(w1 + (size_t)k * 1024);
        float4 x0 = xr[lane * 2], x1 = xr[lane * 2 + 1];
        float4 w0 = wr[lane * 2], w1v = wr[lane * 2 + 1];
        float s = x0.x * w0.x + x0.y * w0.y + x0.z * w0.z + x0.w * w0.w
                + x1.x * w1v.x + x1.y * w1v.y + x1.z * w1v.z + x1.w * w1v.w;
#pragma unroll
        for (int off = 32; off > 0; off >>= 1) s += __shfl_down(s, off);
        if (lane == 0) qp[b * Hdim + k] = s + b1[k];
    }
}

// ---------------- pure MFMA GEMM: P = A . w1t^T, P stored bf16 ----------------
// grid = NTILES*4; block = 128 rows x 128 cols tile of P.
__global__ __launch_bounds__(256, 4) void gemm_kernel(
    const unsigned short* __restrict__ Adec,   // 32000 x 512 bf16
    const unsigned short* __restrict__ Atgt,   // 16384 x 512 bf16
    const unsigned short* __restrict__ Wbf,    // 512 x 1024 bf16 (full w1)
    unsigned short* __restrict__ P)            // 48384 x 512 bf16
{
    __shared__ struct { unsigned short A[128][64]; unsigned short W[128][64]; } u;

    const int tid  = threadIdx.x;
    const int lane = tid & 63;
    const int w    = tid >> 6;

    const int mt = blockIdx.x >> 2;
    const int n0 = (blockIdx.x & 3) << 7;
    const bool is_dec = (mt < DEC_TILES);
    const int m0 = (is_dec ? mt : mt - DEC_TILES) << 7;
    const unsigned short* __restrict__ A = is_dec ? Adec : Atgt;
    const int base = is_dec ? m0 : Vdim + m0;   // P row base

    // staging: lane L loads 16B -> LDS base + L*16; phys col8 (L&7) holds
    // logical k-group (L&7)^(L>>3)  (XOR swizzle, verified rounds 1-3)
    const int sr = lane >> 3;
    const int sc = (lane & 7) ^ sr;
    const unsigned short* gA = A   + (size_t)(m0 + w * 32 + sr) * 512  + sc * 8;
    const unsigned short* gW = Wbf + (size_t)(n0 + w * 32 + sr) * 1024 + 512 + sc * 8;

    f32x16 acc00, acc01, acc10, acc11;
#pragma unroll
    for (int i = 0; i < 16; ++i) { acc00[i] = 0.f; acc01[i] = 0.f; acc10[i] = 0.f; acc11[i] = 0.f; }

    const int wm  = (w & 1) << 6;
    const int wn  = (w >> 1) << 6;
    const int l31 = lane & 31;
    const int kh  = lane >> 5;

    for (int h0 = 0; h0 < Hdim; h0 += 64) {
        __syncthreads();
#pragma unroll
        for (int i = 0; i < 4; ++i) {
            __builtin_amdgcn_global_load_lds(
                (const __attribute__((address_space(1))) unsigned int*)(gA + i * 8 * 512),
                (__attribute__((address_space(3))) unsigned int*)(&u.A[w * 32 + i * 8][0]),
                16, 0, 0);
            __builtin_amdgcn_global_load_lds(
                (const __attribute__((address_space(1))) unsigned int*)(gW + i * 8 * 1024),
                (__attribute__((address_space(3))) unsigned int*)(&u.W[w * 32 + i * 8][0]),
                16, 0, 0);
        }
        gA += 64; gW += 64;
        __syncthreads();
#pragma unroll
        for (int s = 0; s < 4; ++s) {
            const int g  = s * 2 + kh;
            const int ca = ((g ^ (l31 & 7)) << 3);
            short8 a0 = *(const short8*)&u.A[wm + l31][ca];
            short8 a1 = *(const short8*)&u.A[wm + l31 + 32][ca];
            short8 b0 = *(const short8*)&u.W[wn + l31][ca];
            short8 b1 = *(const short8*)&u.W[wn + l31 + 32][ca];
            acc00 = __builtin_amdgcn_mfma_f32_32x32x16_bf16(a0, b0, acc00, 0, 0, 0);
            acc01 = __builtin_amdgcn_mfma_f32_32x32x16_bf16(a0, b1, acc01, 0, 0, 0);
            acc10 = __builtin_amdgcn_mfma_f32_32x32x16_bf16(a1, b0, acc10, 0, 0, 0);
            acc11 = __builtin_amdgcn_mfma_f32_32x32x16_bf16(a1, b1, acc11, 0, 0, 0);
        }
    }

    // C/D layout (verified m74/m101): col=lane&31, row=(r&3)+8*(r>>2)+4*(lane>>5)
#pragma unroll
    for (int r = 0; r < 16; ++r) {
        const int ra = (r & 3) + ((r >> 2) << 3) + (kh << 2);   // 0..31
        const size_t r0 = (size_t)(base + wm + ra) * 512 + n0;
        const size_t r1 = (size_t)(base + wm + 32 + ra) * 512 + n0;
        P[r0 + wn + l31]      = (unsigned short)bfr(acc00[r]);
        P[r0 + wn + 32 + l31] = (unsigned short)bfr(acc01[r]);
        P[r1 + wn + l31]      = (unsigned short)bfr(acc10[r]);
        P[r1 + wn + 32 + l31] = (unsigned short)bfr(acc11[r]);
    }
}

// ---------------- epilogue: out = reduce_n relu(P + qp) . w2, + mask ----------------
// 378 blocks x 256 thr; wave handles 32 rows, lane owns 8 n-cols.
__global__ __launch_bounds__(256) void epi_kernel(
    const unsigned short* __restrict__ P, const float* __restrict__ qp,
    const float* __restrict__ w2, const float* __restrict__ mask,
    float* __restrict__ out)
{
    const int blk = blockIdx.x;
    const int tid = threadIdx.x;
    const int lane = tid & 63;
    const int wv = tid >> 6;
    const int c0 = lane * 8;
    const bool is_dec = (blk < DEC_TILES);

    const float4 w20 = *(const float4*)(w2 + c0);
    const float4 w21 = *(const float4*)(w2 + c0 + 4);

    if (is_dec) {
        const int row0 = blk * 128 + wv * 32;
        float4 q0[8], q1[8];
#pragma unroll
        for (int b = 0; b < 8; ++b) {
            q0[b] = *(const float4*)(qp + b * Hdim + c0);
            q1[b] = *(const float4*)(qp + b * Hdim + c0 + 4);
        }
        for (int i = 0; i < 32; ++i) {
            const uint4 pv = *(const uint4*)(P + (size_t)(row0 + i) * 512 + c0);
            float p[8];
            p[0] = lo16f(pv.x); p[1] = hi16f(pv.x);
            p[2] = lo16f(pv.y); p[3] = hi16f(pv.y);
            p[4] = lo16f(pv.z); p[5] = hi16f(pv.z);
            p[6] = lo16f(pv.w); p[7] = hi16f(pv.w);
            float s[8];
#pragma unroll
            for (int b = 0; b < 8; ++b) {
                float t;
                t  = fmaxf(p[0] + q0[b].x, 0.f) * w20.x;
                t += fmaxf(p[1] + q0[b].y, 0.f) * w20.y;
                t += fmaxf(p[2] + q0[b].z, 0.f) * w20.z;
                t += fmaxf(p[3] + q0[b].w, 0.f) * w20.w;
                t += fmaxf(p[4] + q1[b].x, 0.f) * w21.x;
                t += fmaxf(p[5] + q1[b].y, 0.f) * w21.y;
                t += fmaxf(p[6] + q1[b].z, 0.f) * w21.z;
                t += fmaxf(p[7] + q1[b].w, 0.f) * w21.w;
                s[b] = t;
            }
#pragma unroll
            for (int off = 32; off > 0; off >>= 1)
#pragma unroll
                for (int b = 0; b < 8; ++b) s[b] += __shfl_xor(s[b], off);
            if (lane == 0) {
#pragma unroll
                for (int b = 0; b < 8; ++b)
                    out[(size_t)b * OUTW + row0 + i] = s[b];
            }
        }
    } else {
        const int rl0 = (blk - DEC_TILES) * 128 + wv * 32;  // 0..16383
        const int b = rl0 >> 11;                            // 32-row group never crosses batch
        const float4 q0 = *(const float4*)(qp + b * Hdim + c0);
        const float4 q1 = *(const float4*)(qp + b * Hdim + c0 + 4);
        for (int i = 0; i < 32; ++i) {
            const int rr = rl0 + i;
            const uint4 pv = *(const uint4*)(P + (size_t)(Vdim + rr) * 512 + c0);
            float p[8];
            p[0] = lo16f(pv.x); p[1] = hi16f(pv.x);
            p[2] = lo16f(pv.y); p[3] = hi16f(pv.y);
            p[4] = lo16f(pv.z); p[5] = hi16f(pv.z);
            p[6] = lo16f(pv.w); p[7] = hi16f(pv.w);
            float s;
            s  = fmaxf(p[0] + q0.x, 0.f) * w20.x;
            s += fmaxf(p[1] + q0.y, 0.f) * w20.y;
            s += fmaxf(p[2] + q0.z, 0.f) * w20.z;
            s += fmaxf(p[3] + q0.w, 0.f) * w20.w;
            s += fmaxf(p[4] + q1.x, 0.f) * w21.x;
            s += fmaxf(p[5] + q1.y, 0.f) * w21.y;
            s += fmaxf(p[6] + q1.z, 0.f) * w21.z;
            s += fmaxf(p[7] + q1.w, 0.f) * w21.w;
#pragma unroll
            for (int off = 32; off > 0; off >>= 1) s += __shfl_xor(s, off);
            if (lane == 0) {
                const int t = rr & 2047;
                const float mv = mask[b * Tdim + t];
                out[(size_t)b * OUTW + Vdim + t] = mv * s - 1000.f * (1.f - mv);
            }
        }
    }
}

extern "C" void kernel_launch(void* const* d_in, const int* in_sizes, int n_in,
                              void* d_out, int out_size, void* d_ws, size_t ws_size,
                              hipStream_t stream) {
    const float* input_embeds  = (const float*)d_in[0];  // (8,1,512)
    const float* target_embeds = (const float*)d_in[1];  // (8,2048,512)
    const float* input_mask    = (const float*)d_in[2];  // (8,2048)
    const float* w1            = (const float*)d_in[3];  // (512,1024)
    const float* b1            = (const float*)d_in[4];  // (512,)
    const float* w2            = (const float*)d_in[5];  // (512,)
    const float* decoder_w     = (const float*)d_in[6];  // (32000,512)
    float* out = (float*)d_out;

    // ws: qp 16 KB | P bf16 48384x512 (49.5 MB) | dec bf16 | tgt bf16 | w1 bf16
    float* qp = (float*)d_ws;
    unsigned short* Pbuf  = (unsigned short*)((char*)d_ws + 16384);
    unsigned short* decbf = Pbuf + (size_t)PROWS * Hdim;
    unsigned short* tgtbf = decbf + (size_t)Vdim * Hdim;
    unsigned short* w1bf  = tgtbf + (size_t)Bdim * Tdim * Hdim;

    prep_kernel<<<CVT_BLOCKS + QP_BLOCKS, 256, 0, stream>>>(
        decoder_w, target_embeds, w1, input_embeds, b1, decbf, tgtbf, w1bf, qp);
    gemm_kernel<<<NTILES * 4, 256, 0, stream>>>(decbf, tgtbf, w1bf, Pbuf);
    epi_kernel<<<NTILES, 256, 0, stream>>>(Pbuf, qp, w2, input_mask, out);
}